// Round 1
// baseline (45.267 us; speedup 1.0000x reference)
//
#include <hip/hip_runtime.h>
#include <math.h>

// Problem constants
constexpr int kD   = 128;   // model dim
constexpr int kE   = 256;   // experts
constexpr int kTok = 4 * 512; // B*T

__global__ __launch_bounds__(256) void moe_fused(
    const float* __restrict__ x,        // [kTok, kD]
    const float* __restrict__ gate_w,   // [kD, kE]
    const float* __restrict__ gate_b,   // [kE]
    const float* __restrict__ expert_w, // [kE, kD, kD]
    const float* __restrict__ w1m,      // [kD, kD]
    const float* __restrict__ b1,       // [kD]
    const float* __restrict__ w2m,      // [kD, kD]
    const float* __restrict__ b2,       // [kD]
    float* __restrict__ out_avg,        // [kTok, kD]
    float* __restrict__ out_cons)       // [kTok]
{
    const int tok = blockIdx.x;
    const int t   = threadIdx.x;

    __shared__ float xs[kD];
    __shared__ float red[kE];
    __shared__ float sval[kE];
    __shared__ int   sidx[kE];
    __shared__ float wavg[kD];
    __shared__ float vv[kD];
    __shared__ float outp[kD];
    __shared__ float swv[2];
    __shared__ int   sei[2];

    // ---- load x row into LDS ----
    if (t < kD) xs[t] = x[(size_t)tok * kD + t];
    __syncthreads();

    // ---- gate logits: thread t owns expert t ----
    float logit = gate_b[t];
    #pragma unroll 8
    for (int d = 0; d < kD; ++d)
        logit = fmaf(xs[d], gate_w[d * kE + t], logit);

    // ---- softmax: max reduce over 256 ----
    red[t] = logit; __syncthreads();
    for (int s = 128; s > 0; s >>= 1) {
        if (t < s) red[t] = fmaxf(red[t], red[t + s]);
        __syncthreads();
    }
    const float mx = red[0];
    __syncthreads();

    const float ex = expf(logit - mx);
    red[t] = ex; __syncthreads();
    for (int s = 128; s > 0; s >>= 1) {
        if (t < s) red[t] += red[t + s];
        __syncthreads();
    }
    const float p = ex / red[0];
    __syncthreads();

    // ---- top-1 argmax (ties -> lower index, matching lax.top_k) ----
    sval[t] = p; sidx[t] = t; __syncthreads();
    for (int s = 128; s > 0; s >>= 1) {
        if (t < s) {
            if (sval[t + s] > sval[t] ||
                (sval[t + s] == sval[t] && sidx[t + s] < sidx[t])) {
                sval[t] = sval[t + s]; sidx[t] = sidx[t + s];
            }
        }
        __syncthreads();
    }
    if (t == 0) { sei[0] = sidx[0]; swv[0] = sval[0]; }
    __syncthreads();
    const int   i0 = sei[0];
    const float v0 = swv[0];
    __syncthreads();

    // ---- top-2: mask out i0, argmax again ----
    sval[t] = (t == i0) ? -INFINITY : p; sidx[t] = t; __syncthreads();
    for (int s = 128; s > 0; s >>= 1) {
        if (t < s) {
            if (sval[t + s] > sval[t] ||
                (sval[t + s] == sval[t] && sidx[t + s] < sidx[t])) {
                sval[t] = sval[t + s]; sidx[t] = sidx[t + s];
            }
        }
        __syncthreads();
    }
    if (t == 0) { sei[1] = sidx[0]; swv[1] = sval[0]; }
    __syncthreads();
    const int   i1 = sei[1];
    const float v1 = swv[1];

    const float denom = v0 + v1 + 1e-6f;
    const float wt0 = v0 / denom;
    const float wt1 = v1 / denom;

    // ---- expert matvecs: group g = t/128 handles expert i_g ----
    const int g = t >> 7;        // 0 or 1
    const int o = t & 127;       // output dim
    const int   eg = (g == 0) ? i0 : i1;
    const float wg = (g == 0) ? wt0 : wt1;

    const float* Ew = expert_w + (size_t)eg * kD * kD;
    float y = 0.f;
    #pragma unroll 8
    for (int d = 0; d < kD; ++d)
        y = fmaf(xs[d], Ew[d * kD + o], y);

    // combine weighted average (pre-SwiGLU)
    if (g == 0) wavg[o] = wt0 * y;
    __syncthreads();
    if (g == 1) wavg[o] += wt1 * y;
    __syncthreads();

    // ---- SwiGLU: group0 -> g-path (w1), group1 -> v-path (w2) ----
    const float* W  = (g == 0) ? w1m : w2m;
    const float* bb = (g == 0) ? b1  : b2;
    float a2 = bb[o];
    #pragma unroll 8
    for (int d = 0; d < kD; ++d)
        a2 = fmaf(wavg[d], W[d * kD + o], a2);

    if (g == 1) vv[o] = a2;
    __syncthreads();
    if (g == 0) {
        const float gg  = a2;
        const float res = gg * (1.f / (1.f + expf(-gg))) * vv[o];
        outp[o] = res;
        out_avg[(size_t)tok * kD + o] = res;
    }
    __syncthreads();

    // ---- weighted variance -> consensus ----
    const float diff = y - outp[o];
    red[t] = wg * diff * diff;
    __syncthreads();
    for (int s = 128; s > 0; s >>= 1) {
        if (t < s) red[t] += red[t + s];
        __syncthreads();
    }
    if (t == 0) out_cons[tok] = expf(-red[0] / (float)kD);
}

extern "C" void kernel_launch(void* const* d_in, const int* in_sizes, int n_in,
                              void* d_out, int out_size, void* d_ws, size_t ws_size,
                              hipStream_t stream) {
    const float* x        = (const float*)d_in[0];
    const float* gate_w   = (const float*)d_in[1];
    const float* gate_b   = (const float*)d_in[2];
    const float* expert_w = (const float*)d_in[3];
    const float* w1m      = (const float*)d_in[4];
    const float* b1       = (const float*)d_in[5];
    const float* w2m      = (const float*)d_in[6];
    const float* b2       = (const float*)d_in[7];

    float* out      = (float*)d_out;
    float* out_avg  = out;                  // [kTok, kD]
    float* out_cons = out + (size_t)kTok * kD; // [kTok]

    moe_fused<<<kTok, 256, 0, stream>>>(x, gate_w, gate_b, expert_w,
                                        w1m, b1, w2m, b2, out_avg, out_cons);
}